// Round 4
// baseline (1360.280 us; speedup 1.0000x reference)
//
#include <hip/hip_runtime.h>
#include <hip/hip_bf16.h>

typedef unsigned short u16;
typedef unsigned int u32;

constexpr int NN = 50000;   // nodes
constexpr int NE = 400000;  // edges

__device__ __forceinline__ float bf2f(u16 u) {
    union { u32 i; float f; } v; v.i = ((u32)u) << 16; return v.f;
}
__device__ __forceinline__ u16 f2bf(float f) {
    union { float f; u32 i; } v; v.f = f;
    u32 r = v.i + 0x7fffu + ((v.i >> 16) & 1u);
    return (u16)(r >> 16);
}
// dtype-adaptive float load: isbf=1 -> bf16 storage, isbf=0 -> f32 storage
__device__ __forceinline__ float ldf(const void* p, size_t i, int isbf) {
    if (isbf) return bf2f(((const u16*)p)[i]);
    return ((const float*)p)[i];
}
__device__ __forceinline__ float clampf(float v) {
    // kills inf AND NaN (fmaxf(NaN,x)=x on HIP); never binds for sane values
    return fminf(fmaxf(v, -1e4f), 1e4f);
}

// ---------------- static device scratch (independent of d_ws) ----------------
__device__ int   g_flag;
__device__ int   g_counter;
__device__ float g_qe1[256], g_qe2[256];
__device__ float g_ps1[128], g_pd1[128], g_ps2[512], g_pd2[512];
__device__ float g_bnsum[128], g_bnsumsq[128], g_bnscale[128], g_bnshift[128];
__device__ int   g_deg[NN], g_start[NN], g_cur[NN];
__device__ int   g_eidx[NE];
__device__ float g_sbuf[NN * 4], g_dbuf[NN * 4];
__device__ float g_mz[NN * 8];
__device__ float g_alpha[(size_t)NE * 4];
__device__ float g_xbuf[(size_t)NN * 128];
__device__ u16   g_share[(size_t)NN * 128];
__device__ float g_acc2[(size_t)NN * 128];

// ---------------- dtype detect + init ----------------
__global__ void k_detect(const u16* x) {
    if (threadIdx.x == 0) {
        int cnt = 0;
        for (int i = 0; i < 64; i++) {
            u16 u = x[2 * i];            // even u16 index
            int ex = (u >> 7) & 0xff;
            if (ex >= 100 && ex <= 140) cnt++;
        }
        g_flag = (cnt >= 40) ? 1 : 0;
        g_counter = 0;
    }
}
__global__ void k_zero() {
    int i = blockIdx.x * blockDim.x + threadIdx.x;
    if (i < NN) g_deg[i] = 0;
    if (i < 128) { g_bnsum[i] = 0.f; g_bnsumsq[i] = 0.f; }
}

// Folded projections: qe[k*4+h]=sum_c We[k,h*C+c]*ae[h,c];
// ps/pd[h*C+k]=sum_c W[k,h*C+c]*as/ad[h,c]
__global__ void k_prep(const void* we1, const void* ae1, const void* we2, const void* ae2,
                       const void* w1, const void* as1, const void* ad1,
                       const void* w2, const void* as2, const void* ad2) {
    int isbf = g_flag;
    int t = threadIdx.x;          // 256
    {
        int k = t >> 2, hd = t & 3;
        float a1 = 0.f;
        for (int c = 0; c < 32; c++)
            a1 += ldf(we1, k * 128 + hd * 32 + c, isbf) * ldf(ae1, hd * 32 + c, isbf);
        g_qe1[t] = a1;
        float a2 = 0.f;
        for (int c = 0; c < 128; c++)
            a2 += ldf(we2, k * 512 + hd * 128 + c, isbf) * ldf(ae2, hd * 128 + c, isbf);
        g_qe2[t] = a2;
    }
    if (t < 128) {
        int h = t >> 5, k = t & 31;
        float a = 0.f, b = 0.f;
        for (int c = 0; c < 32; c++) {
            float w = ldf(w1, k * 128 + h * 32 + c, isbf);
            a += w * ldf(as1, h * 32 + c, isbf);
            b += w * ldf(ad1, h * 32 + c, isbf);
        }
        g_ps1[t] = a; g_pd1[t] = b;
    }
    for (int r = 0; r < 2; r++) {
        int idx = t + 256 * r;
        int h = idx >> 7, k = idx & 127;
        float a = 0.f, b = 0.f;
        for (int c = 0; c < 128; c++) {
            float w = ldf(w2, k * 512 + h * 128 + c, isbf);
            a += w * ldf(as2, h * 128 + c, isbf);
            b += w * ldf(ad2, h * 128 + c, isbf);
        }
        g_ps2[idx] = a; g_pd2[idx] = b;
    }
}

// ---------------- CSR build ----------------
__global__ void k_deg(const int* __restrict__ dstp) {
    int e = blockIdx.x * blockDim.x + threadIdx.x;
    if (e < NE) atomicAdd(&g_deg[dstp[e]], 1);
}
__global__ void k_start() {
    int n = blockIdx.x * blockDim.x + threadIdx.x;
    if (n < NN) {
        int d = g_deg[n];
        int s = atomicAdd(&g_counter, d);
        g_start[n] = s; g_cur[n] = s;
    }
}
__global__ void k_scatter(const int* __restrict__ dstp) {
    int e = blockIdx.x * blockDim.x + threadIdx.x;
    if (e < NE) {
        int slot = atomicAdd(&g_cur[dstp[e]], 1);
        g_eidx[slot] = e;
    }
}

// ---------------- layer 1 node transform ----------------
__global__ __launch_bounds__(256) void k_node1(
    const void* x, const int* __restrict__ ntype,
    const void* ne1, const void* w1, const void* wres1, const void* b1) {
    __shared__ float xl[16][32];
    __shared__ float xil[16][32];
    __shared__ float nel[96];
    __shared__ int ntl[16];
    int isbf = g_flag;
    int t = threadIdx.x;
    int n0 = blockIdx.x * 16;
    if (t < 96) nel[t] = ldf(ne1, t, isbf);
    if (t >= 128 && t < 144) {
        int nn = t - 128; int n = n0 + nn;
        ntl[nn] = (n < NN) ? ntype[n] : 0;
    }
    __syncthreads();
    for (int idx = t; idx < 512; idx += 256) {
        int nn = idx >> 5, k = idx & 31; int n = n0 + nn;
        float xv = (n < NN) ? ldf(x, (size_t)n * 32 + k, isbf) : 0.f;
        xl[nn][k] = xv;
        xil[nn][k] = xv + nel[ntl[nn] * 32 + k];
    }
    __syncthreads();
    int j = t & 127, nrow = t >> 7;
    float b1v = ldf(b1, j, isbf);
    for (int sub = 0; sub < 8; sub++) {
        int nn = nrow + 2 * sub; int n = n0 + nn;
        float acch = 0.f, accr = 0.f;
#pragma unroll 4
        for (int k = 0; k < 32; k++) {
            acch += xil[nn][k] * ldf(w1, k * 128 + j, isbf);
            accr += xl[nn][k] * ldf(wres1, k * 128 + j, isbf);
        }
        if (n < NN) {
            g_share[(size_t)n * 128 + j] = f2bf(clampf(acch));
            g_xbuf[(size_t)n * 128 + j] = clampf(accr + b1v);
        }
    }
    if (t < 128) {
        int nn = t >> 3, q = t & 7, h = q & 3;
        int n = n0 + nn;
        const float* pv = (q < 4) ? g_ps1 : g_pd1;
        float a = 0.f;
#pragma unroll 4
        for (int k = 0; k < 32; k++) a += xil[nn][k] * pv[h * 32 + k];
        if (n < NN) {
            if (q < 4) g_sbuf[n * 4 + h] = a;
            else       g_dbuf[n * 4 + h] = a;
        }
    }
}

// ---------------- edge attention logits (lyr selects qe/ee fold set) -------
__global__ __launch_bounds__(256) void k_edge(
    const int* __restrict__ srcp, const int* __restrict__ dstp,
    const int* __restrict__ etype, const void* eattr,
    const void* ee, int lyr) {
    __shared__ float eel[256];   // [4][64]
    __shared__ float qel[256];   // [64][4]
    int isbf = g_flag;
    int t = threadIdx.x;
    const float* qe = (lyr == 1) ? g_qe1 : g_qe2;   // device-side symbol ref (fix)
    eel[t] = ldf(ee, t, isbf);
    qel[t] = qe[t];
    __syncthreads();
    int e = blockIdx.x * 256 + t;
    if (e >= NE) return;
    int et = etype[e];
    const float* eerow = eel + et * 64;
    float el0 = 0.f, el1 = 0.f, el2 = 0.f, el3 = 0.f;
#pragma unroll 4
    for (int kb = 0; kb < 64; kb++) {
        float ev = ldf(eattr, (size_t)e * 64 + kb, isbf) + eerow[kb];
        const float* q0 = qel + kb * 4;
        el0 += ev * q0[0]; el1 += ev * q0[1];
        el2 += ev * q0[2]; el3 += ev * q0[3];
    }
    int ss = srcp[e], dd = dstp[e];
    float a0 = g_sbuf[ss * 4 + 0] + g_dbuf[dd * 4 + 0] + el0;
    float a1 = g_sbuf[ss * 4 + 1] + g_dbuf[dd * 4 + 1] + el1;
    float a2 = g_sbuf[ss * 4 + 2] + g_dbuf[dd * 4 + 2] + el2;
    float a3 = g_sbuf[ss * 4 + 3] + g_dbuf[dd * 4 + 3] + el3;
    a0 = a0 > 0.f ? a0 : 0.2f * a0;
    a1 = a1 > 0.f ? a1 : 0.2f * a1;
    a2 = a2 > 0.f ? a2 : 0.2f * a2;
    a3 = a3 > 0.f ? a3 : 0.2f * a3;
    *(float4*)(g_alpha + 4 * (size_t)e) = make_float4(
        clampf(a0), clampf(a1), clampf(a2), clampf(a3));
}

// ---------------- per-node softmax stats ----------------
__global__ __launch_bounds__(256) void k_softmax() {
    int lane = threadIdx.x & 63;
    int n = blockIdx.x * 4 + (threadIdx.x >> 6);
    if (n >= NN) return;
    int st = g_start[n], dg = g_deg[n];
    float m0 = -1e30f, m1 = -1e30f, m2 = -1e30f, m3 = -1e30f;
    for (int i = lane; i < dg; i += 64) {
        int e = g_eidx[st + i];
        float4 a = *(const float4*)(g_alpha + 4 * (size_t)e);
        m0 = fmaxf(m0, a.x); m1 = fmaxf(m1, a.y);
        m2 = fmaxf(m2, a.z); m3 = fmaxf(m3, a.w);
    }
    for (int mk = 32; mk >= 1; mk >>= 1) {
        m0 = fmaxf(m0, __shfl_xor(m0, mk)); m1 = fmaxf(m1, __shfl_xor(m1, mk));
        m2 = fmaxf(m2, __shfl_xor(m2, mk)); m3 = fmaxf(m3, __shfl_xor(m3, mk));
    }
    if (m0 < -1e29f) m0 = 0.f;
    if (m1 < -1e29f) m1 = 0.f;
    if (m2 < -1e29f) m2 = 0.f;
    if (m3 < -1e29f) m3 = 0.f;
    float z0 = 0.f, z1 = 0.f, z2 = 0.f, z3 = 0.f;
    for (int i = lane; i < dg; i += 64) {
        int e = g_eidx[st + i];
        float4 a = *(const float4*)(g_alpha + 4 * (size_t)e);
        z0 += expf(a.x - m0); z1 += expf(a.y - m1);
        z2 += expf(a.z - m2); z3 += expf(a.w - m3);
    }
    for (int mk = 32; mk >= 1; mk >>= 1) {
        z0 += __shfl_xor(z0, mk); z1 += __shfl_xor(z1, mk);
        z2 += __shfl_xor(z2, mk); z3 += __shfl_xor(z3, mk);
    }
    if (lane == 0) {
        *(float4*)(g_mz + (size_t)n * 8) = make_float4(m0, m1, m2, m3);
        *(float4*)(g_mz + (size_t)n * 8 + 4) = make_float4(
            1.f / (z0 + 1e-16f), 1.f / (z1 + 1e-16f),
            1.f / (z2 + 1e-16f), 1.f / (z3 + 1e-16f));
    }
}

// ---------------- edge-parallel coef ----------------
__global__ __launch_bounds__(256) void k_coef(const int* __restrict__ dstp) {
    int e = blockIdx.x * 256 + threadIdx.x;
    if (e >= NE) return;
    float4 a = *(const float4*)(g_alpha + 4 * (size_t)e);
    int dd = dstp[e];
    float4 mm = *(const float4*)(g_mz + (size_t)dd * 8);
    float4 iv = *(const float4*)(g_mz + (size_t)dd * 8 + 4);
    *(float4*)(g_alpha + 4 * (size_t)e) = make_float4(
        expf(a.x - mm.x) * iv.x, expf(a.y - mm.y) * iv.y,
        expf(a.z - mm.z) * iv.z, expf(a.w - mm.w) * iv.w);
}

// ---------------- layer 1 gather ----------------
__global__ __launch_bounds__(256) void k_gather1(const int* __restrict__ srcp) {
    int lane = threadIdx.x & 63;
    int n = blockIdx.x * 4 + (threadIdx.x >> 6);
    if (n >= NN) return;
    int st = g_start[n], dg = g_deg[n];
    if (dg == 0) return;
    int j0 = 2 * lane;
    int hd = j0 >> 5;
    float acc0 = 0.f, acc1 = 0.f;
    for (int base = 0; base < dg; base += 64) {
        int i = base + lane;
        int sidx = 0; float c0 = 0.f, c1 = 0.f, c2 = 0.f, c3 = 0.f;
        if (i < dg) {
            int e = g_eidx[st + i];
            float4 c = *(const float4*)(g_alpha + 4 * (size_t)e);
            sidx = srcp[e];
            c0 = c.x; c1 = c.y; c2 = c.z; c3 = c.w;
        }
        int cnt = min(64, dg - base);
        for (int jj = 0; jj < cnt; jj++) {
            int s2 = __shfl(sidx, jj);
            float b0 = __shfl(c0, jj), b1 = __shfl(c1, jj);
            float b2v = __shfl(c2, jj), b3 = __shfl(c3, jj);
            float cs = hd == 0 ? b0 : hd == 1 ? b1 : hd == 2 ? b2v : b3;
            u32 hv = *(const u32*)(g_share + (size_t)s2 * 128 + j0);
            acc0 += bf2f((u16)(hv & 0xffff)) * cs;
            acc1 += bf2f((u16)(hv >> 16)) * cs;
        }
    }
    float* xp = g_xbuf + (size_t)n * 128 + j0;
    xp[0] = clampf(xp[0] + acc0);
    xp[1] = clampf(xp[1] + acc1);
}

// ---------------- batch norm ----------------
__global__ __launch_bounds__(256) void k_bnstats() {
    int t = threadIdx.x;
    int j = t & 127;
    int r0 = blockIdx.x * 2 + (t >> 7);
    float s = 0.f, ss = 0.f;
    for (int r = r0; r < NN; r += 500) {
        float v = g_xbuf[(size_t)r * 128 + j];
        s += v; ss += v * v;
    }
    atomicAdd(&g_bnsum[j], s);
    atomicAdd(&g_bnsumsq[j], ss);
}
__global__ void k_bnfin(const void* gamma, const void* beta) {
    int isbf = g_flag;
    int j = threadIdx.x;  // 128
    float mu = g_bnsum[j] * (1.f / NN);
    float var = fmaxf(g_bnsumsq[j] * (1.f / NN) - mu * mu, 0.f);
    float rstd = rsqrtf(var + 1e-5f);
    float sc = ldf(gamma, j, isbf) * rstd;
    g_bnscale[j] = sc;
    g_bnshift[j] = ldf(beta, j, isbf) - mu * sc;
}

// ---------------- layer 2 prep ----------------
__global__ __launch_bounds__(256) void k_pre2(
    const int* __restrict__ ntype, const void* ne2,
    const void* wres2, const void* b2) {
    __shared__ float xbn[8][128];
    __shared__ float xi2s[8][128];
    __shared__ int ntl[8];
    int isbf = g_flag;
    int t = threadIdx.x;
    int n0 = blockIdx.x * 8;
    if (t < 8) { int n = n0 + t; ntl[t] = (n < NN) ? ntype[n] : 0; }
    __syncthreads();
    for (int idx = t; idx < 1024; idx += 256) {
        int nn = idx >> 7, jj = idx & 127; int n = n0 + nn;
        float v = (n < NN) ? g_xbuf[(size_t)n * 128 + jj] : 0.f;
        float xb = v * g_bnscale[jj] + g_bnshift[jj];
        xbn[nn][jj] = xb;
        xi2s[nn][jj] = xb + ldf(ne2, ntl[nn] * 128 + jj, isbf);
    }
    __syncthreads();
    int j = t & 127, half = t >> 7;
    float b2v = ldf(b2, j, isbf);
    for (int q = 0; q < 4; q++) {
        int nn = half * 4 + q; int n = n0 + nn;
        float accr = 0.f;
#pragma unroll 4
        for (int k = 0; k < 128; k++)
            accr += xbn[nn][k] * ldf(wres2, k * 128 + j, isbf);
        if (n < NN) g_acc2[(size_t)n * 128 + j] = clampf(accr + b2v);
    }
    if (t < 64) {
        int nn = t >> 3, q = t & 7, h = q & 3;
        int n = n0 + nn;
        const float* pv = (q < 4) ? g_ps2 : g_pd2;
        float a = 0.f;
#pragma unroll 4
        for (int k = 0; k < 128; k++) a += xi2s[nn][k] * pv[h * 128 + k];
        if (n < NN) {
            if (q < 4) g_sbuf[n * 4 + h] = a;
            else       g_dbuf[n * 4 + h] = a;
        }
    }
}

// ---------------- layer 2 per-head GEMM ----------------
__global__ __launch_bounds__(256) void k_node2h(
    const int* __restrict__ ntype, const void* ne2, const void* w2, int h) {
    __shared__ float xi2s[8][128];
    __shared__ int ntl[8];
    int isbf = g_flag;
    int t = threadIdx.x;
    int n0 = blockIdx.x * 8;
    if (t < 8) { int n = n0 + t; ntl[t] = (n < NN) ? ntype[n] : 0; }
    __syncthreads();
    for (int idx = t; idx < 1024; idx += 256) {
        int nn = idx >> 7, jj = idx & 127; int n = n0 + nn;
        float v = (n < NN) ? g_xbuf[(size_t)n * 128 + jj] : 0.f;
        float xb = v * g_bnscale[jj] + g_bnshift[jj];
        xi2s[nn][jj] = xb + ldf(ne2, ntl[nn] * 128 + jj, isbf);
    }
    __syncthreads();
    int c = t & 127, half = t >> 7;
    int nb = half * 4;
    float a0 = 0.f, a1 = 0.f, a2 = 0.f, a3 = 0.f;
#pragma unroll 4
    for (int k = 0; k < 128; k++) {
        float w = ldf(w2, (size_t)k * 512 + h * 128 + c, isbf);
        a0 += xi2s[nb + 0][k] * w;
        a1 += xi2s[nb + 1][k] * w;
        a2 += xi2s[nb + 2][k] * w;
        a3 += xi2s[nb + 3][k] * w;
    }
    int n = n0 + nb;
    if (n + 0 < NN) g_share[(size_t)(n + 0) * 128 + c] = f2bf(clampf(a0));
    if (n + 1 < NN) g_share[(size_t)(n + 1) * 128 + c] = f2bf(clampf(a1));
    if (n + 2 < NN) g_share[(size_t)(n + 2) * 128 + c] = f2bf(clampf(a2));
    if (n + 3 < NN) g_share[(size_t)(n + 3) * 128 + c] = f2bf(clampf(a3));
}

// ---------------- layer 2 per-head gather ----------------
__global__ __launch_bounds__(256) void k_gather2h(const int* __restrict__ srcp, int h) {
    int lane = threadIdx.x & 63;
    int n = blockIdx.x * 4 + (threadIdx.x >> 6);
    if (n >= NN) return;
    int st = g_start[n], dg = g_deg[n];
    if (dg == 0) return;
    int c0 = 2 * lane;
    float acc0 = 0.f, acc1 = 0.f;
    for (int base = 0; base < dg; base += 64) {
        int i = base + lane;
        int sidx = 0; float ch = 0.f;
        if (i < dg) {
            int e = g_eidx[st + i];
            ch = g_alpha[4 * (size_t)e + h];
            sidx = srcp[e];
        }
        int cnt = min(64, dg - base);
        for (int jj = 0; jj < cnt; jj++) {
            int s2 = __shfl(sidx, jj);
            float cc = __shfl(ch, jj);
            u32 hv = *(const u32*)(g_share + (size_t)s2 * 128 + c0);
            acc0 += bf2f((u16)(hv & 0xffff)) * cc;
            acc1 += bf2f((u16)(hv >> 16)) * cc;
        }
    }
    float* ap = g_acc2 + (size_t)n * 128 + c0;
    ap[0] = clampf(ap[0] + 0.25f * acc0);
    ap[1] = clampf(ap[1] + 0.25f * acc1);
}

// ---------------- final cast (dtype-adaptive output) ----------------
__global__ __launch_bounds__(256) void k_final(void* outp) {
    int isbf = g_flag;
    int i = blockIdx.x * 256 + threadIdx.x;
    int idx = i * 2;
    if (idx >= NN * 128) return;
    float f0 = g_acc2[idx], f1 = g_acc2[idx + 1];
    if (isbf) {
        u32 pk = ((u32)f2bf(f0)) | (((u32)f2bf(f1)) << 16);
        *(u32*)((u16*)outp + idx) = pk;
    } else {
        *(float2*)((float*)outp + idx) = make_float2(f0, f1);
    }
}

// ---------------- launcher ----------------
extern "C" void kernel_launch(void* const* d_in, const int* in_sizes, int n_in,
                              void* d_out, int out_size, void* d_ws, size_t ws_size,
                              hipStream_t stream) {
    const void* x     = d_in[0];
    const int* ei     = (const int*)d_in[1];
    const int* ntype  = (const int*)d_in[2];
    const void* eattr = d_in[3];
    const int* etype  = (const int*)d_in[4];
    const void* ne1   = d_in[5];
    const void* w1    = d_in[6];
    const void* we1   = d_in[7];
    const void* asrc1 = d_in[8];
    const void* adst1 = d_in[9];
    const void* aedge1= d_in[10];
    const void* ee1   = d_in[11];
    const void* wres1 = d_in[12];
    const void* b1    = d_in[13];
    const void* gamma = d_in[14];
    const void* beta  = d_in[15];
    const void* ne2   = d_in[16];
    const void* w2    = d_in[17];
    const void* we2   = d_in[18];
    const void* asrc2 = d_in[19];
    const void* adst2 = d_in[20];
    const void* aedge2= d_in[21];
    const void* ee2   = d_in[22];
    const void* wres2 = d_in[23];
    const void* b2    = d_in[24];
    (void)in_sizes; (void)n_in; (void)out_size; (void)d_ws; (void)ws_size;

    const int* srcp = ei;
    const int* dstp = ei + NE;

    k_detect<<<1, 64, 0, stream>>>((const u16*)x);
    k_zero<<<196, 256, 0, stream>>>();
    k_prep<<<1, 256, 0, stream>>>(we1, aedge1, we2, aedge2,
                                  w1, asrc1, adst1, w2, asrc2, adst2);
    k_deg<<<1563, 256, 0, stream>>>(dstp);
    k_start<<<196, 256, 0, stream>>>();
    k_scatter<<<1563, 256, 0, stream>>>(dstp);

    // ---- layer 1 ----
    k_node1<<<3125, 256, 0, stream>>>(x, ntype, ne1, w1, wres1, b1);
    k_edge<<<1563, 256, 0, stream>>>(srcp, dstp, etype, eattr, ee1, 1);
    k_softmax<<<12500, 256, 0, stream>>>();
    k_coef<<<1563, 256, 0, stream>>>(dstp);
    k_gather1<<<12500, 256, 0, stream>>>(srcp);

    // ---- batch norm ----
    k_bnstats<<<250, 256, 0, stream>>>();
    k_bnfin<<<1, 128, 0, stream>>>(gamma, beta);

    // ---- layer 2 ----
    k_pre2<<<6250, 256, 0, stream>>>(ntype, ne2, wres2, b2);
    k_edge<<<1563, 256, 0, stream>>>(srcp, dstp, etype, eattr, ee2, 2);
    k_softmax<<<12500, 256, 0, stream>>>();
    k_coef<<<1563, 256, 0, stream>>>(dstp);
    for (int h = 0; h < 4; h++) {
        k_node2h<<<6250, 256, 0, stream>>>(ntype, ne2, w2, h);
        k_gather2h<<<12500, 256, 0, stream>>>(srcp, h);
    }
    k_final<<<12500, 256, 0, stream>>>(d_out);
}